// Round 7
// baseline (295.806 us; speedup 1.0000x reference)
//
#include <hip/hip_runtime.h>
#include <hip/hip_bf16.h>

typedef __bf16 bf16;
typedef __attribute__((ext_vector_type(8))) __bf16 bf16x8;
typedef __attribute__((ext_vector_type(4))) __bf16 bf16x4;
typedef __attribute__((ext_vector_type(4))) float f32x4;

#define DIMD  1024
#define SEQ   2048
#define BATCH 2
#define HEADS 16
#define INNER 1024
#define QKVN  3072   // q(1024) | k(1024) | v(1024)
#define ROWS  (BATCH*SEQ)  // 4096
#define LOG2E 1.44269504f

// ---------------- LayerNorm over the SEQUENCE axis (per (b,d)) ----------------
__global__ void ln_partial(const float* __restrict__ x,
                           float* __restrict__ psum, float* __restrict__ psq) {
    const int nc = blockIdx.x;   // 0..63
    const int b  = blockIdx.y;   // 0..1
    const int t  = threadIdx.x;  // 0..255
    const float* xp = x + ((size_t)b*SEQ + (size_t)nc*32)*DIMD;
    float s0=0,s1=0,s2=0,s3=0,q0=0,q1=0,q2=0,q3=0;
    for (int r=0; r<32; ++r) {
        const float* row = xp + (size_t)r*DIMD;
        float v0=row[t], v1=row[t+256], v2=row[t+512], v3=row[t+768];
        s0+=v0; q0+=v0*v0; s1+=v1; q1+=v1*v1;
        s2+=v2; q2+=v2*v2; s3+=v3; q3+=v3*v3;
    }
    float* ps = psum + ((size_t)b*64 + nc)*DIMD;
    float* pq = psq  + ((size_t)b*64 + nc)*DIMD;
    ps[t]=s0; ps[t+256]=s1; ps[t+512]=s2; ps[t+768]=s3;
    pq[t]=q0; pq[t+256]=q1; pq[t+512]=q2; pq[t+768]=q3;
}

__global__ void ln_finalize(const float* __restrict__ psum, const float* __restrict__ psq,
                            const float* __restrict__ g,
                            float* __restrict__ scale, float* __restrict__ shift) {
    const int d = blockIdx.x*256 + threadIdx.x;  // 0..1023
    const int b = blockIdx.y;
    float s=0.f, q=0.f;
    for (int nc=0; nc<64; ++nc) {
        s += psum[((size_t)b*64+nc)*DIMD + d];
        q += psq [((size_t)b*64+nc)*DIMD + d];
    }
    const float inv_n = 1.f/(float)SEQ;
    float mean = s*inv_n;
    float var  = q*inv_n - mean*mean;
    var = fmaxf(var, 1e-5f);
    scale[b*DIMD+d] = g[d]*rsqrtf(var);
    shift[b*DIMD+d] = mean;
}

__global__ void ln_apply(const float* __restrict__ x,
                         const float* __restrict__ scale, const float* __restrict__ shift,
                         bf16* __restrict__ xn) {
    size_t idx = ((size_t)blockIdx.x*256 + threadIdx.x)*4;
    int b = (int)(idx >> 21);          // SEQ*DIMD = 2^21
    int d = (int)(idx & (DIMD-1));
    f32x4 v  = *reinterpret_cast<const f32x4*>(x + idx);
    f32x4 sc = *reinterpret_cast<const f32x4*>(scale + (size_t)b*DIMD + d);
    f32x4 sh = *reinterpret_cast<const f32x4*>(shift + (size_t)b*DIMD + d);
    bf16x4 o;
    o.x = (bf16)((v.x - sh.x)*sc.x);
    o.y = (bf16)((v.y - sh.y)*sc.y);
    o.z = (bf16)((v.z - sh.z)*sc.z);
    o.w = (bf16)((v.w - sh.w)*sc.w);
    *reinterpret_cast<bf16x4*>(xn + idx) = o;
}

// ---------------- f32 -> bf16 cast with scale (weights) ----------------
__global__ void castk(const float* __restrict__ s, bf16* __restrict__ d, int n, float scl) {
    int i = (blockIdx.x*256 + threadIdx.x)*4;
    if (i >= n) return;
    f32x4 v = *reinterpret_cast<const f32x4*>(s + i);
    bf16x4 o; o.x=(bf16)(v.x*scl); o.y=(bf16)(v.y*scl); o.z=(bf16)(v.z*scl); o.w=(bf16)(v.w*scl);
    *reinterpret_cast<bf16x4*>(d + i) = o;
}

// ---------------- async global->LDS (16B, m97 pattern) ----------------
__device__ __forceinline__ void gload16(const void* g, void* l) {
    __builtin_amdgcn_global_load_lds(
        (const __attribute__((address_space(1))) unsigned int*)g,
        (__attribute__((address_space(3))) unsigned int*)l,
        16, 0, 0);
}

// ---------------- bt-GEMM (m97 structure): C[m][n] = sum_k A[m][k]*B[n][k] ----
__device__ inline void store_out(float* p, float v) { *p = v; }
__device__ inline void store_out(bf16*  p, float v) { *p = (bf16)v; }

template <typename OT>
__global__ __launch_bounds__(256, 2)
void gemm_bt(const bf16* __restrict__ A, const bf16* __restrict__ B,
             OT* __restrict__ C, int M, int N, int K) {
    __shared__ bf16 As[128*64];
    __shared__ bf16 Bs[128*64];
    const int t = threadIdx.x;
    const int wave = t >> 6, lane = t & 63;
    const int wr = wave >> 1, wc = wave & 1;
    const int m0 = blockIdx.y*128, n0 = blockIdx.x*128;
    const int lr = lane & 15, lg = lane >> 4;
    const int srow = wave*32 + (lane>>3);   // +8*i
    const int scol = (lane&7)*8;            // bf16 elems (16B)

    f32x4 acc[4][4];
    #pragma unroll
    for (int i=0;i<4;++i)
        #pragma unroll
        for (int j=0;j<4;++j) acc[i][j] = (f32x4){0.f,0.f,0.f,0.f};

    for (int k0=0; k0<K; k0+=64) {
        #pragma unroll
        for (int i=0;i<4;++i) {
            gload16(A + (size_t)(m0+srow+8*i)*K + k0 + scol, As + (srow+8*i)*64 + scol);
            gload16(B + (size_t)(n0+srow+8*i)*K + k0 + scol, Bs + (srow+8*i)*64 + scol);
        }
        __syncthreads();
        #pragma unroll
        for (int kk=0; kk<2; ++kk) {
            bf16x8 a[4], b[4];
            #pragma unroll
            for (int mi=0;mi<4;++mi)
                a[mi] = *reinterpret_cast<const bf16x8*>(As + (wr*64+mi*16+lr)*64 + kk*32+lg*8);
            #pragma unroll
            for (int ni=0;ni<4;++ni)
                b[ni] = *reinterpret_cast<const bf16x8*>(Bs + (wc*64+ni*16+lr)*64 + kk*32+lg*8);
            #pragma unroll
            for (int mi=0;mi<4;++mi)
                #pragma unroll
                for (int ni=0;ni<4;++ni)
                    acc[mi][ni] = __builtin_amdgcn_mfma_f32_16x16x32_bf16(a[mi], b[ni], acc[mi][ni], 0, 0, 0);
        }
        __syncthreads();
    }
    #pragma unroll
    for (int mi=0;mi<4;++mi)
        #pragma unroll
        for (int ni=0;ni<4;++ni)
            #pragma unroll
            for (int r=0;r<4;++r) {
                int row = m0 + wr*64 + mi*16 + lg*4 + r;
                int col = n0 + wc*64 + ni*16 + lr;
                store_out(&C[(size_t)row*N + col], acc[mi][ni][r]);
            }
}

// ---------------- V transpose: qkv V part -> vT[b][h][d][n] ----------------
__global__ __launch_bounds__(256)
void transpose_v(const bf16* __restrict__ qkv, bf16* __restrict__ vT) {
    __shared__ bf16 tile[64][72];
    const int nt = blockIdx.x, h = blockIdx.y, b = blockIdx.z;
    const int t = threadIdx.x;
    const bf16* src = qkv + ((size_t)(b*SEQ + nt*64))*QKVN + 2*INNER + h*64;
    #pragma unroll
    for (int i=0;i<2;++i) {
        int c = t + 256*i, row = c>>3, col = (c&7)*8;
        *reinterpret_cast<bf16x8*>(&tile[row][col]) =
            *reinterpret_cast<const bf16x8*>(src + (size_t)row*QKVN + col);
    }
    __syncthreads();
    bf16* dst = vT + ((size_t)(b*HEADS + h))*64*SEQ + nt*64;
    #pragma unroll
    for (int i=0;i<2;++i) {
        int c = t + 256*i, d = c>>3, n0 = (c&7)*8;
        bf16x8 v;
        #pragma unroll
        for (int j=0;j<8;++j) v[j] = tile[n0+j][d];
        *reinterpret_cast<bf16x8*>(dst + (size_t)d*SEQ + n0) = v;
    }
}

// ---------------- fused flash attention, dual-batch, 48KB LDS ----------------
// Block = (qt, h), 512 threads = 8 waves (waves 0-3 batch 0, 4-7 batch 1).
// K and V single-buffered (two barriers/iter):
//   [top] commit V(T); QK(T); BAR1; commit K(T+1); prefetch; softmax(T);
//   P->LDS; PV(T); BAR2.
// Fast exp2 (v_exp_f32) via __builtin_amdgcn_exp2f; Q prescaled 0.125*log2e.

#define ATTN_BARRIER()                                         \
    __builtin_amdgcn_sched_barrier(0);                         \
    asm volatile("s_waitcnt lgkmcnt(0)" ::: "memory");         \
    __builtin_amdgcn_s_barrier();                              \
    __builtin_amdgcn_sched_barrier(0)

#define ATTN_ITER(CUR, T)                                                          \
  {                                                                                \
    /* commit V(T) from regs staged in iter T-1 (prologue for T=0) */              \
    *reinterpret_cast<bf16x8*>(&VTArr[0][st_off]) = vrA;                           \
    *reinterpret_cast<bf16x8*>(&VTArr[1][st_off]) = vrB;                           \
    /* QK(T): K(T) resident in Ks since iter T-1 */                                \
    f32x4 p[4];                                                                    \
    __builtin_amdgcn_s_setprio(1);                                                 \
    _Pragma("unroll")                                                              \
    for (int j=0;j<4;++j) {                                                        \
      f32x4 sj = (f32x4){0.f,0.f,0.f,0.f};                                         \
      bf16x8 kf0 = *reinterpret_cast<const bf16x8*>(&myK[kr_off0 + j*1024]);       \
      sj = __builtin_amdgcn_mfma_f32_16x16x32_bf16(kf0, qf0, sj, 0,0,0);           \
      bf16x8 kf1 = *reinterpret_cast<const bf16x8*>(&myK[kr_off1 + j*1024]);       \
      sj = __builtin_amdgcn_mfma_f32_16x16x32_bf16(kf1, qf1, sj, 0,0,0);           \
      p[j] = sj;                                                                   \
    }                                                                              \
    __builtin_amdgcn_s_setprio(0);                                                 \
    ATTN_BARRIER();  /* BAR1: QK done everywhere; V(T) visible everywhere */       \
    /* commit K(T+1) */                                                            \
    if ((T)+1 < 32) {                                                              \
      *reinterpret_cast<bf16x8*>(&KsArr[0][st_off]) = krA;                         \
      *reinterpret_cast<bf16x8*>(&KsArr[1][st_off]) = krB;                         \
    }                                                                              \
    /* prefetch K(T+2) into regs */                                                \
    if ((T)+2 < 32) {                                                              \
      krA = *reinterpret_cast<const bf16x8*>(kbase0 + (size_t)(((T)+2)*64+srow)*QKVN + scol); \
      krB = *reinterpret_cast<const bf16x8*>(kbase1 + (size_t)(((T)+2)*64+srow)*QKVN + scol); \
    }                                                                              \
    /* prefetch V(T+1) regs + bias(T+1) */                                         \
    if ((T)+1 < 32) {                                                              \
      vrA = *reinterpret_cast<const bf16x8*>(vtb0 + (size_t)srow*SEQ + ((T)+1)*64 + scol);    \
      vrB = *reinterpret_cast<const bf16x8*>(vtb1 + (size_t)srow*SEQ + ((T)+1)*64 + scol);    \
      const float* bp = brow + ((T)+1)*64 + 4*g;                                   \
      breg[(CUR)^1][0] = *reinterpret_cast<const f32x4*>(bp);                      \
      breg[(CUR)^1][1] = *reinterpret_cast<const f32x4*>(bp + 16);                 \
      breg[(CUR)^1][2] = *reinterpret_cast<const f32x4*>(bp + 32);                 \
      breg[(CUR)^1][3] = *reinterpret_cast<const f32x4*>(bp + 48);                 \
    }                                                                              \
    /* softmax(T) in exp2 domain, fast v_exp_f32 */                                \
    float vmax = -3.0e38f;                                                         \
    _Pragma("unroll")                                                              \
    for (int j=0;j<4;++j)                                                          \
      _Pragma("unroll")                                                            \
      for (int r=0;r<4;++r) {                                                      \
        float v = __builtin_fmaf(breg[CUR][j][r], LOG2E, p[j][r]);                 \
        p[j][r] = v; vmax = fmaxf(vmax, v);                                        \
      }                                                                            \
    if (!__all(vmax <= m + 11.5f)) {                                               \
      vmax = fmaxf(vmax, __shfl_xor(vmax, 16));                                    \
      vmax = fmaxf(vmax, __shfl_xor(vmax, 32));                                    \
      float mnew = fmaxf(m, vmax);                                                 \
      float sc = __builtin_amdgcn_exp2f(m - mnew);                                 \
      m = mnew; l *= sc;                                                           \
      float s0 = __shfl(sc, 20*g+0), s1 = __shfl(sc, 20*g+1);                      \
      float s2 = __shfl(sc, 20*g+2), s3 = __shfl(sc, 20*g+3);                      \
      _Pragma("unroll")                                                            \
      for (int j=0;j<4;++j) {                                                      \
        accO[j][0]*=s0; accO[j][1]*=s1; accO[j][2]*=s2; accO[j][3]*=s3;            \
      }                                                                            \
    }                                                                              \
    float rsum = 0.f;                                                              \
    _Pragma("unroll")                                                              \
    for (int j=0;j<4;++j) {                                                        \
      bf16x4 pk;                                                                   \
      _Pragma("unroll")                                                            \
      for (int r=0;r<4;++r) {                                                      \
        float e = __builtin_amdgcn_exp2f(p[j][r] - m);                             \
        rsum += e; pk[r] = (bf16)e;                                                \
      }                                                                            \
      *reinterpret_cast<bf16x4*>(&myP[pw_off[j]]) = pk;                            \
    }                                                                              \
    rsum += __shfl_xor(rsum, 16);                                                  \
    rsum += __shfl_xor(rsum, 32);                                                  \
    l += rsum;                                                                     \
    asm volatile("" ::: "memory");                                                 \
    /* PV(T): V(T) visible since BAR1 */                                           \
    __builtin_amdgcn_s_setprio(1);                                                 \
    {                                                                              \
      bf16x8 pa0 = *reinterpret_cast<const bf16x8*>(&myP[pr_off0]);                \
      bf16x8 pa1 = *reinterpret_cast<const bf16x8*>(&myP[pr_off1]);                \
      _Pragma("unroll")                                                            \
      for (int j=0;j<4;++j) {                                                      \
        bf16x8 vf0 = *reinterpret_cast<const bf16x8*>(&myV[kr_off0 + j*1024]);     \
        accO[j] = __builtin_amdgcn_mfma_f32_16x16x32_bf16(pa0, vf0, accO[j], 0,0,0); \
        bf16x8 vf1 = *reinterpret_cast<const bf16x8*>(&myV[kr_off1 + j*1024]);     \
        accO[j] = __builtin_amdgcn_mfma_f32_16x16x32_bf16(pa1, vf1, accO[j], 0,0,0); \
      }                                                                            \
    }                                                                              \
    __builtin_amdgcn_s_setprio(0);                                                 \
    ATTN_BARRIER();  /* BAR2: PV done -> V/K/P safe to overwrite next iter */      \
  }

__global__ __launch_bounds__(512, 4)
void attn_kernel(const bf16* __restrict__ qkv, const bf16* __restrict__ vTg,
                 const float* __restrict__ bias, bf16* __restrict__ oh) {
    __shared__ bf16 KsArr[2][64*64];   // [batch] single-buffered
    __shared__ bf16 VTArr[2][64*64];   // [batch] single-buffered
    __shared__ bf16 Ps[2][64*64];      // [batch]

    const int qt = blockIdx.x, h = blockIdx.y;
    const int t = threadIdx.x;
    const int w = t >> 6, lane = t & 63;
    const int wb = w >> 2;                // batch of this wave
    const int wq = w & 3;                 // q-subtile within batch
    const int lr = lane & 15, g = lane >> 4;
    const int q0 = qt*64;
    const int swz = lr & 7;

    // swizzled LDS offsets (elements)
    const int kr_off0 = lr*64 + ((g^swz)*8);          // + j*1024
    const int kr_off1 = lr*64 + (((4+g)^swz)*8);
    const int pr_off0 = (wq*16+lr)*64 + ((g^swz)*8);
    const int pr_off1 = (wq*16+lr)*64 + (((4+g)^swz)*8);
    int pw_off[4];
    #pragma unroll
    for (int j=0;j<4;++j)
        pw_off[j] = (wq*16+lr)*64 + (((2*j+(g>>1))^swz)*8) + (g&1)*4;

    bf16* myK = (bf16*)KsArr[wb];
    bf16* myV = (bf16*)VTArr[wb];
    bf16* myP = Ps[wb];

    // staging map: 512 threads cover one 64x64 tile (1 b128 each)
    const int srow = t>>3;                 // 0..63
    const int scol = (t&7)*8;
    const int st_off = srow*64 + (((t&7) ^ (srow&7))*8);

    // Q fragments in registers (prescaled by 0.125*log2e via Wq cast)
    const bf16* qrow = qkv + ((size_t)(wb*SEQ + q0 + wq*16 + lr))*QKVN + h*64;
    bf16x8 qf0 = *reinterpret_cast<const bf16x8*>(qrow + g*8);
    bf16x8 qf1 = *reinterpret_cast<const bf16x8*>(qrow + 32 + g*8);

    const bf16* kbase0 = qkv + INNER + h*64;
    const bf16* kbase1 = qkv + (size_t)SEQ*QKVN + INNER + h*64;
    const bf16* vtb0   = vTg + (size_t)h*64*SEQ;
    const bf16* vtb1   = vTg + (size_t)(HEADS + h)*64*SEQ;
    const float* brow  = bias + ((size_t)h*SEQ + (size_t)(q0 + wq*16 + lr))*SEQ;

    bf16x8 krA, krB, vrA, vrB;
    f32x4 breg[2][4];

    // prologue: K(0) -> LDS; regs: V(0), K(1); bias(0) -> breg[0]
    *reinterpret_cast<bf16x8*>(&KsArr[0][st_off]) =
        *reinterpret_cast<const bf16x8*>(kbase0 + (size_t)srow*QKVN + scol);
    *reinterpret_cast<bf16x8*>(&KsArr[1][st_off]) =
        *reinterpret_cast<const bf16x8*>(kbase1 + (size_t)srow*QKVN + scol);
    vrA = *reinterpret_cast<const bf16x8*>(vtb0 + (size_t)srow*SEQ + scol);
    vrB = *reinterpret_cast<const bf16x8*>(vtb1 + (size_t)srow*SEQ + scol);
    krA = *reinterpret_cast<const bf16x8*>(kbase0 + (size_t)(64+srow)*QKVN + scol);
    krB = *reinterpret_cast<const bf16x8*>(kbase1 + (size_t)(64+srow)*QKVN + scol);
    breg[0][0] = *reinterpret_cast<const f32x4*>(brow + 4*g);
    breg[0][1] = *reinterpret_cast<const f32x4*>(brow + 16 + 4*g);
    breg[0][2] = *reinterpret_cast<const f32x4*>(brow + 32 + 4*g);
    breg[0][3] = *reinterpret_cast<const f32x4*>(brow + 48 + 4*g);
    ATTN_BARRIER();

    float m = -__builtin_inff();
    float l = 0.f;
    f32x4 accO[4];
    #pragma unroll
    for (int j=0;j<4;++j) accO[j] = (f32x4){0.f,0.f,0.f,0.f};

    for (int t2 = 0; t2 < 32; t2 += 2) {
        ATTN_ITER(0, t2);
        ATTN_ITER(1, t2+1);
    }

    // epilogue: O /= l ; lane's accO[j][r] is q = wq*16+4g+r, d = j*16+lr
    float linv = 1.f/l;
    float li0 = __shfl(linv, 20*g + 0);
    float li1 = __shfl(linv, 20*g + 1);
    float li2 = __shfl(linv, 20*g + 2);
    float li3 = __shfl(linv, 20*g + 3);
    float li[4] = {li0, li1, li2, li3};
    bf16* ob = oh + ((size_t)(wb*SEQ + q0 + wq*16 + 4*g))*INNER + h*64;
    #pragma unroll
    for (int r=0;r<4;++r)
        #pragma unroll
        for (int j=0;j<4;++j)
            ob[(size_t)r*INNER + j*16 + lr] = (bf16)(accO[j][r]*li[r]);
}

// ---------------- host launcher ----------------
extern "C" void kernel_launch(void* const* d_in, const int* in_sizes, int n_in,
                              void* d_out, int out_size, void* d_ws, size_t ws_size,
                              hipStream_t stream) {
    const float* x    = (const float*)d_in[0];
    const float* bias = (const float*)d_in[1];
    const float* g    = (const float*)d_in[2];
    const float* Wq   = (const float*)d_in[3];
    const float* Wkv  = (const float*)d_in[4];
    const float* Wo   = (const float*)d_in[5];
    float* out = (float*)d_out;

    char* ws = (char*)d_ws;
    bf16*  xn    = (bf16*)(ws);                       //  8,388,608 B (dead after QKV gemm)
    bf16*  vT    = (bf16*)(ws);                       //  overlays xn
    bf16*  wqkv  = (bf16*)(ws + 8388608);             //  6,291,456 B
    bf16*  wo    = (bf16*)(ws + 14680064);            //  2,097,152 B
    bf16*  qkv   = (bf16*)(ws + 16777216);            // 25,165,824 B
    bf16*  oh    = (bf16*)(ws + 41943040);            //  8,388,608 B
    float* psum  = (float*)(ws + 50331648);           //    524,288 B
    float* psq   = (float*)(ws + 50855936);           //    524,288 B
    float* scale = (float*)(ws + 51380224);           //      8,192 B
    float* shift = (float*)(ws + 51388416);           //      8,192 B

    ln_partial <<<dim3(64,2), 256, 0, stream>>>(x, psum, psq);
    ln_finalize<<<dim3(4,2),  256, 0, stream>>>(psum, psq, g, scale, shift);
    ln_apply   <<<dim3(4096), 256, 0, stream>>>(x, scale, shift, xn);

    // Wq prescaled by 0.125*log2e (attention scale folded + exp2-domain softmax)
    castk<<<dim3(1024), 256, 0, stream>>>(Wq,  wqkv,           1048576, 0.125f*LOG2E);
    castk<<<dim3(2048), 256, 0, stream>>>(Wkv, wqkv + 1048576, 2097152, 1.0f);
    castk<<<dim3(1024), 256, 0, stream>>>(Wo,  wo,             1048576, 1.0f);

    // QKV = xn @ [Wq;Wkv]^T : M=4096, N=3072, K=1024
    gemm_bt<bf16><<<dim3(24,32), 256, 0, stream>>>(xn, wqkv, qkv, ROWS, QKVN, DIMD);

    // V -> V^T (per (b,h): [2048 n][64 d] -> [64 d][2048 n]); vT overlays dead xn
    transpose_v<<<dim3(32,16,2), 256, 0, stream>>>(qkv, vT);

    // fused attention (both batches per block) -> out_heads [4096,1024] bf16
    attn_kernel<<<dim3(32,16), 512, 0, stream>>>(qkv, vT, bias, oh);

    // final = oh @ Wo^T : M=4096, N=1024, K=1024, fp32 out
    gemm_bt<float><<<dim3(8,32), 256, 0, stream>>>(oh, wo, out, ROWS, INNER, INNER);
}

// Round 8
// 208.421 us; speedup vs baseline: 1.4193x; 1.4193x over previous
//
#include <hip/hip_runtime.h>
#include <hip/hip_bf16.h>

typedef __bf16 bf16;
typedef __attribute__((ext_vector_type(8))) __bf16 bf16x8;
typedef __attribute__((ext_vector_type(4))) __bf16 bf16x4;
typedef __attribute__((ext_vector_type(4))) float f32x4;

#define DIMD  1024
#define SEQ   2048
#define BATCH 2
#define HEADS 16
#define INNER 1024
#define QKVN  3072   // q(1024) | k(1024) | v(1024)
#define ROWS  (BATCH*SEQ)  // 4096
#define LOG2E 1.44269504f

// ---------------- LayerNorm over the SEQUENCE axis (per (b,d)) ----------------
__global__ void ln_partial(const float* __restrict__ x,
                           float* __restrict__ psum, float* __restrict__ psq) {
    const int nc = blockIdx.x;   // 0..63
    const int b  = blockIdx.y;   // 0..1
    const int t  = threadIdx.x;  // 0..255
    const float* xp = x + ((size_t)b*SEQ + (size_t)nc*32)*DIMD;
    float s0=0,s1=0,s2=0,s3=0,q0=0,q1=0,q2=0,q3=0;
    for (int r=0; r<32; ++r) {
        const float* row = xp + (size_t)r*DIMD;
        float v0=row[t], v1=row[t+256], v2=row[t+512], v3=row[t+768];
        s0+=v0; q0+=v0*v0; s1+=v1; q1+=v1*v1;
        s2+=v2; q2+=v2*v2; s3+=v3; q3+=v3*v3;
    }
    float* ps = psum + ((size_t)b*64 + nc)*DIMD;
    float* pq = psq  + ((size_t)b*64 + nc)*DIMD;
    ps[t]=s0; ps[t+256]=s1; ps[t+512]=s2; ps[t+768]=s3;
    pq[t]=q0; pq[t+256]=q1; pq[t+512]=q2; pq[t+768]=q3;
}

__global__ void ln_finalize(const float* __restrict__ psum, const float* __restrict__ psq,
                            const float* __restrict__ g,
                            float* __restrict__ scale, float* __restrict__ shift) {
    const int d = blockIdx.x*256 + threadIdx.x;  // 0..1023
    const int b = blockIdx.y;
    float s=0.f, q=0.f;
    for (int nc=0; nc<64; ++nc) {
        s += psum[((size_t)b*64+nc)*DIMD + d];
        q += psq [((size_t)b*64+nc)*DIMD + d];
    }
    const float inv_n = 1.f/(float)SEQ;
    float mean = s*inv_n;
    float var  = q*inv_n - mean*mean;
    var = fmaxf(var, 1e-5f);
    scale[b*DIMD+d] = g[d]*rsqrtf(var);
    shift[b*DIMD+d] = mean;
}

__global__ void ln_apply(const float* __restrict__ x,
                         const float* __restrict__ scale, const float* __restrict__ shift,
                         bf16* __restrict__ xn) {
    size_t idx = ((size_t)blockIdx.x*256 + threadIdx.x)*4;
    int b = (int)(idx >> 21);          // SEQ*DIMD = 2^21
    int d = (int)(idx & (DIMD-1));
    f32x4 v  = *reinterpret_cast<const f32x4*>(x + idx);
    f32x4 sc = *reinterpret_cast<const f32x4*>(scale + (size_t)b*DIMD + d);
    f32x4 sh = *reinterpret_cast<const f32x4*>(shift + (size_t)b*DIMD + d);
    bf16x4 o;
    o.x = (bf16)((v.x - sh.x)*sc.x);
    o.y = (bf16)((v.y - sh.y)*sc.y);
    o.z = (bf16)((v.z - sh.z)*sc.z);
    o.w = (bf16)((v.w - sh.w)*sc.w);
    *reinterpret_cast<bf16x4*>(xn + idx) = o;
}

// ---------------- f32 -> bf16 cast with scale (weights) ----------------
__global__ void castk(const float* __restrict__ s, bf16* __restrict__ d, int n, float scl) {
    int i = (blockIdx.x*256 + threadIdx.x)*4;
    if (i >= n) return;
    f32x4 v = *reinterpret_cast<const f32x4*>(s + i);
    bf16x4 o; o.x=(bf16)(v.x*scl); o.y=(bf16)(v.y*scl); o.z=(bf16)(v.z*scl); o.w=(bf16)(v.w*scl);
    *reinterpret_cast<bf16x4*>(d + i) = o;
}

// ---------------- async global->LDS (16B, m97 pattern) ----------------
__device__ __forceinline__ void gload16(const void* g, void* l) {
    __builtin_amdgcn_global_load_lds(
        (const __attribute__((address_space(1))) unsigned int*)g,
        (__attribute__((address_space(3))) unsigned int*)l,
        16, 0, 0);
}

// ---------------- bt-GEMM (m97 structure): C[m][n] = sum_k A[m][k]*B[n][k] ----
__device__ inline void store_out(float* p, float v) { *p = v; }
__device__ inline void store_out(bf16*  p, float v) { *p = (bf16)v; }

template <typename OT>
__global__ __launch_bounds__(256, 2)
void gemm_bt(const bf16* __restrict__ A, const bf16* __restrict__ B,
             OT* __restrict__ C, int M, int N, int K) {
    __shared__ bf16 As[128*64];
    __shared__ bf16 Bs[128*64];
    const int t = threadIdx.x;
    const int wave = t >> 6, lane = t & 63;
    const int wr = wave >> 1, wc = wave & 1;
    const int m0 = blockIdx.y*128, n0 = blockIdx.x*128;
    const int lr = lane & 15, lg = lane >> 4;
    const int srow = wave*32 + (lane>>3);   // +8*i
    const int scol = (lane&7)*8;            // bf16 elems (16B)

    f32x4 acc[4][4];
    #pragma unroll
    for (int i=0;i<4;++i)
        #pragma unroll
        for (int j=0;j<4;++j) acc[i][j] = (f32x4){0.f,0.f,0.f,0.f};

    for (int k0=0; k0<K; k0+=64) {
        #pragma unroll
        for (int i=0;i<4;++i) {
            gload16(A + (size_t)(m0+srow+8*i)*K + k0 + scol, As + (srow+8*i)*64 + scol);
            gload16(B + (size_t)(n0+srow+8*i)*K + k0 + scol, Bs + (srow+8*i)*64 + scol);
        }
        __syncthreads();
        #pragma unroll
        for (int kk=0; kk<2; ++kk) {
            bf16x8 a[4], b[4];
            #pragma unroll
            for (int mi=0;mi<4;++mi)
                a[mi] = *reinterpret_cast<const bf16x8*>(As + (wr*64+mi*16+lr)*64 + kk*32+lg*8);
            #pragma unroll
            for (int ni=0;ni<4;++ni)
                b[ni] = *reinterpret_cast<const bf16x8*>(Bs + (wc*64+ni*16+lr)*64 + kk*32+lg*8);
            #pragma unroll
            for (int mi=0;mi<4;++mi)
                #pragma unroll
                for (int ni=0;ni<4;++ni)
                    acc[mi][ni] = __builtin_amdgcn_mfma_f32_16x16x32_bf16(a[mi], b[ni], acc[mi][ni], 0, 0, 0);
        }
        __syncthreads();
    }
    #pragma unroll
    for (int mi=0;mi<4;++mi)
        #pragma unroll
        for (int ni=0;ni<4;++ni)
            #pragma unroll
            for (int r=0;r<4;++r) {
                int row = m0 + wr*64 + mi*16 + lg*4 + r;
                int col = n0 + wc*64 + ni*16 + lr;
                store_out(&C[(size_t)row*N + col], acc[mi][ni][r]);
            }
}

// ---------------- V transpose: qkv V part -> vT[b][h][d][n] ----------------
__global__ __launch_bounds__(256)
void transpose_v(const bf16* __restrict__ qkv, bf16* __restrict__ vT) {
    __shared__ bf16 tile[64][72];
    const int nt = blockIdx.x, h = blockIdx.y, b = blockIdx.z;
    const int t = threadIdx.x;
    const bf16* src = qkv + ((size_t)(b*SEQ + nt*64))*QKVN + 2*INNER + h*64;
    #pragma unroll
    for (int i=0;i<2;++i) {
        int c = t + 256*i, row = c>>3, col = (c&7)*8;
        *reinterpret_cast<bf16x8*>(&tile[row][col]) =
            *reinterpret_cast<const bf16x8*>(src + (size_t)row*QKVN + col);
    }
    __syncthreads();
    bf16* dst = vT + ((size_t)(b*HEADS + h))*64*SEQ + nt*64;
    #pragma unroll
    for (int i=0;i<2;++i) {
        int c = t + 256*i, d = c>>3, n0 = (c&7)*8;
        bf16x8 v;
        #pragma unroll
        for (int j=0;j<8;++j) v[j] = tile[n0+j][d];
        *reinterpret_cast<bf16x8*>(dst + (size_t)d*SEQ + n0) = v;
    }
}

// ---------------- fused flash attention: 128 q-rows / block ----------------
// 256 threads = 4 waves, each wave owns 32 q-rows (2 fragments qi=0,1).
// Single barrier per KV tile (R5-best schedule), ping-pong K/V LDS,
// XOR-16B swizzle, Q+bias in regs, defer-max, exp2-domain softmax.
// Grid (b=2, qt=16, h=16): b-pairs adjacent for bias L2/L3 reuse.

#define ATTN_BARRIER()                                         \
    __builtin_amdgcn_sched_barrier(0);                         \
    asm volatile("s_waitcnt lgkmcnt(0)" ::: "memory");         \
    __builtin_amdgcn_s_barrier();                              \
    __builtin_amdgcn_sched_barrier(0)

// softmax for one 16-row fragment: p[4] (f32x4), bias bb[4], state m_,l_, acc_
#define SOFTMAX_QI(p, bb, m_, l_, acc_, PWBASE)                                    \
  {                                                                                \
    float vmax = -3.0e38f;                                                         \
    _Pragma("unroll")                                                              \
    for (int j=0;j<4;++j)                                                          \
      _Pragma("unroll")                                                            \
      for (int r=0;r<4;++r) {                                                      \
        float v = __builtin_fmaf(bb[j][r], LOG2E, p[j][r]);                        \
        p[j][r] = v; vmax = fmaxf(vmax, v);                                        \
      }                                                                            \
    if (!__all(vmax <= m_ + 11.5f)) {                                              \
      vmax = fmaxf(vmax, __shfl_xor(vmax, 16));                                    \
      vmax = fmaxf(vmax, __shfl_xor(vmax, 32));                                    \
      float mnew = fmaxf(m_, vmax);                                                \
      float sc = __builtin_amdgcn_exp2f(m_ - mnew);                                \
      m_ = mnew; l_ *= sc;                                                         \
      float s0 = __shfl(sc, 20*g+0), s1 = __shfl(sc, 20*g+1);                      \
      float s2 = __shfl(sc, 20*g+2), s3 = __shfl(sc, 20*g+3);                      \
      _Pragma("unroll")                                                            \
      for (int j=0;j<4;++j) {                                                      \
        acc_[j][0]*=s0; acc_[j][1]*=s1; acc_[j][2]*=s2; acc_[j][3]*=s3;            \
      }                                                                            \
    }                                                                              \
    float rsum = 0.f;                                                              \
    _Pragma("unroll")                                                              \
    for (int j=0;j<4;++j) {                                                        \
      bf16x4 pk;                                                                   \
      _Pragma("unroll")                                                            \
      for (int r=0;r<4;++r) {                                                      \
        float e = __builtin_amdgcn_exp2f(p[j][r] - m_);                            \
        rsum += e; pk[r] = (bf16)e;                                                \
      }                                                                            \
      *reinterpret_cast<bf16x4*>(&myP[(PWBASE) + pwc[j]]) = pk;                    \
    }                                                                              \
    rsum += __shfl_xor(rsum, 16);                                                  \
    rsum += __shfl_xor(rsum, 32);                                                  \
    l_ += rsum;                                                                    \
  }

#define ATTN_ITER(CUR, T)                                                          \
  {                                                                                \
    /* commit staged K/V tile T+1 -> buf CUR^1 */                                  \
    if ((T)+1 < 32) {                                                              \
      *reinterpret_cast<bf16x8*>(&Ks[(CUR)^1][st_off])        = kr0;               \
      *reinterpret_cast<bf16x8*>(&Ks[(CUR)^1][st_off+2048])   = kr1;               \
      *reinterpret_cast<bf16x8*>(&VTs[(CUR)^1][st_off])       = vr0;               \
      *reinterpret_cast<bf16x8*>(&VTs[(CUR)^1][st_off+2048])  = vr1;               \
    }                                                                              \
    /* prefetch K/V tile T+2 into regs (in flight across barrier) */               \
    if ((T)+2 < 32) {                                                              \
      kr0 = *reinterpret_cast<const bf16x8*>(kbase + (size_t)(((T)+2)*64+srow)*QKVN + scol);  \
      kr1 = *reinterpret_cast<const bf16x8*>(kbase + (size_t)(((T)+2)*64+srow+32)*QKVN + scol); \
      vr0 = *reinterpret_cast<const bf16x8*>(vtb + (size_t)srow*SEQ + ((T)+2)*64 + scol);     \
      vr1 = *reinterpret_cast<const bf16x8*>(vtb + (size_t)(srow+32)*SEQ + ((T)+2)*64 + scol); \
    }                                                                              \
    /* bias tile T+1 (both qi) -> breg[CUR^1] */                                   \
    if ((T)+1 < 32) {                                                              \
      const float* bp0 = brow0 + ((T)+1)*64 + 4*g;                                 \
      const float* bp1 = brow1 + ((T)+1)*64 + 4*g;                                 \
      _Pragma("unroll")                                                            \
      for (int j=0;j<4;++j) {                                                      \
        breg[(CUR)^1][0][j] = *reinterpret_cast<const f32x4*>(bp0 + j*16);         \
        breg[(CUR)^1][1][j] = *reinterpret_cast<const f32x4*>(bp1 + j*16);         \
      }                                                                            \
    }                                                                              \
    /* QK qi=0 */                                                                  \
    f32x4 p0[4], p1[4];                                                            \
    __builtin_amdgcn_s_setprio(1);                                                 \
    _Pragma("unroll")                                                              \
    for (int j=0;j<4;++j) {                                                        \
      f32x4 sj = (f32x4){0.f,0.f,0.f,0.f};                                         \
      bf16x8 kf0 = *reinterpret_cast<const bf16x8*>(&Ks[CUR][kr_off0 + j*1024]);   \
      sj = __builtin_amdgcn_mfma_f32_16x16x32_bf16(kf0, qf00, sj, 0,0,0);          \
      bf16x8 kf1 = *reinterpret_cast<const bf16x8*>(&Ks[CUR][kr_off1 + j*1024]);   \
      sj = __builtin_amdgcn_mfma_f32_16x16x32_bf16(kf1, qf01, sj, 0,0,0);          \
      p0[j] = sj;                                                                  \
    }                                                                              \
    __builtin_amdgcn_s_setprio(0);                                                 \
    /* softmax qi=0 (overlaps QK qi=1 below via scheduler) */                      \
    SOFTMAX_QI(p0, breg[CUR][0], m0s, l0s, accO0, 0);                              \
    /* QK qi=1 */                                                                  \
    __builtin_amdgcn_s_setprio(1);                                                 \
    _Pragma("unroll")                                                              \
    for (int j=0;j<4;++j) {                                                        \
      f32x4 sj = (f32x4){0.f,0.f,0.f,0.f};                                         \
      bf16x8 kf0 = *reinterpret_cast<const bf16x8*>(&Ks[CUR][kr_off0 + j*1024]);   \
      sj = __builtin_amdgcn_mfma_f32_16x16x32_bf16(kf0, qf10, sj, 0,0,0);          \
      bf16x8 kf1 = *reinterpret_cast<const bf16x8*>(&Ks[CUR][kr_off1 + j*1024]);   \
      sj = __builtin_amdgcn_mfma_f32_16x16x32_bf16(kf1, qf11, sj, 0,0,0);          \
      p1[j] = sj;                                                                  \
    }                                                                              \
    __builtin_amdgcn_s_setprio(0);                                                 \
    /* softmax qi=1 */                                                             \
    SOFTMAX_QI(p1, breg[CUR][1], m1s, l1s, accO1, 1024);                           \
    asm volatile("" ::: "memory");                                                 \
    /* PV both qi from VTs[CUR] */                                                 \
    __builtin_amdgcn_s_setprio(1);                                                 \
    {                                                                              \
      bf16x8 pa00 = *reinterpret_cast<const bf16x8*>(&myP[pr_off0]);               \
      bf16x8 pa01 = *reinterpret_cast<const bf16x8*>(&myP[pr_off1]);               \
      bf16x8 pa10 = *reinterpret_cast<const bf16x8*>(&myP[1024 + pr_off0]);        \
      bf16x8 pa11 = *reinterpret_cast<const bf16x8*>(&myP[1024 + pr_off1]);        \
      _Pragma("unroll")                                                            \
      for (int j=0;j<4;++j) {                                                      \
        bf16x8 vf0 = *reinterpret_cast<const bf16x8*>(&VTs[CUR][kr_off0 + j*1024]); \
        bf16x8 vf1 = *reinterpret_cast<const bf16x8*>(&VTs[CUR][kr_off1 + j*1024]); \
        accO0[j] = __builtin_amdgcn_mfma_f32_16x16x32_bf16(pa00, vf0, accO0[j], 0,0,0); \
        accO0[j] = __builtin_amdgcn_mfma_f32_16x16x32_bf16(pa01, vf1, accO0[j], 0,0,0); \
        accO1[j] = __builtin_amdgcn_mfma_f32_16x16x32_bf16(pa10, vf0, accO1[j], 0,0,0); \
        accO1[j] = __builtin_amdgcn_mfma_f32_16x16x32_bf16(pa11, vf1, accO1[j], 0,0,0); \
      }                                                                            \
    }                                                                              \
    __builtin_amdgcn_s_setprio(0);                                                 \
    ATTN_BARRIER();                                                                \
  }

__global__ __launch_bounds__(256, 2)
void attn_kernel(const bf16* __restrict__ qkv, const bf16* __restrict__ vTg,
                 const float* __restrict__ bias, bf16* __restrict__ oh) {
    __shared__ bf16 Ks[2][64*64];     // [buf] 8KB each
    __shared__ bf16 VTs[2][64*64];
    __shared__ bf16 Ps[4*32*64];      // per-wave 32x64 (2048 elems)

    const int b = blockIdx.x, qt = blockIdx.y, h = blockIdx.z;
    const int t = threadIdx.x;
    const int w = t >> 6, lane = t & 63;
    const int lr = lane & 15, g = lane >> 4;
    const int q0 = qt*128;
    const int swz = lr & 7;

    // swizzled LDS read offsets (elements)
    const int kr_off0 = lr*64 + ((g^swz)*8);          // + j*1024
    const int kr_off1 = lr*64 + (((4+g)^swz)*8);
    bf16* myP = Ps + w*2048;
    const int pr_off0 = lr*64 + ((g^swz)*8);          // qi=1: +1024
    const int pr_off1 = lr*64 + (((4+g)^swz)*8);
    int pwc[4];
    #pragma unroll
    for (int j=0;j<4;++j)
        pwc[j] = lr*64 + (((2*j+(g>>1))^swz)*8) + (g&1)*4;

    // staging map: 256 threads, two 32-row halves per 64x64 tile
    const int srow = t>>3;                 // 0..31
    const int scol = (t&7)*8;
    const int st_off = srow*64 + (((t&7) ^ (srow&7))*8);   // +2048 for srow+32

    // Q fragments (prescaled by 0.125*log2e): qi=0 rows w*32+lr, qi=1 +16
    const bf16* qrow0 = qkv + ((size_t)(b*SEQ + q0 + w*32 + lr))*QKVN + h*64;
    const bf16* qrow1 = qrow0 + (size_t)16*QKVN;
    bf16x8 qf00 = *reinterpret_cast<const bf16x8*>(qrow0 + g*8);
    bf16x8 qf01 = *reinterpret_cast<const bf16x8*>(qrow0 + 32 + g*8);
    bf16x8 qf10 = *reinterpret_cast<const bf16x8*>(qrow1 + g*8);
    bf16x8 qf11 = *reinterpret_cast<const bf16x8*>(qrow1 + 32 + g*8);

    const bf16* kbase = qkv + (size_t)b*SEQ*QKVN + INNER + h*64;
    const bf16* vtb   = vTg + (size_t)(b*HEADS + h)*64*SEQ;
    const float* brow0 = bias + ((size_t)h*SEQ + (size_t)(q0 + w*32 + lr))*SEQ;
    const float* brow1 = brow0 + (size_t)16*SEQ;

    bf16x8 kr0, kr1, vr0, vr1;
    f32x4 breg[2][2][4];   // [bank][qi][j]

    // prologue: tile0 -> LDS buf0; tile1 -> regs; bias0 -> breg[0]
    *reinterpret_cast<bf16x8*>(&Ks[0][st_off]) =
        *reinterpret_cast<const bf16x8*>(kbase + (size_t)srow*QKVN + scol);
    *reinterpret_cast<bf16x8*>(&Ks[0][st_off+2048]) =
        *reinterpret_cast<const bf16x8*>(kbase + (size_t)(srow+32)*QKVN + scol);
    *reinterpret_cast<bf16x8*>(&VTs[0][st_off]) =
        *reinterpret_cast<const bf16x8*>(vtb + (size_t)srow*SEQ + scol);
    *reinterpret_cast<bf16x8*>(&VTs[0][st_off+2048]) =
        *reinterpret_cast<const bf16x8*>(vtb + (size_t)(srow+32)*SEQ + scol);
    kr0 = *reinterpret_cast<const bf16x8*>(kbase + (size_t)(64+srow)*QKVN + scol);
    kr1 = *reinterpret_cast<const bf16x8*>(kbase + (size_t)(64+srow+32)*QKVN + scol);
    vr0 = *reinterpret_cast<const bf16x8*>(vtb + (size_t)srow*SEQ + 64 + scol);
    vr1 = *reinterpret_cast<const bf16x8*>(vtb + (size_t)(srow+32)*SEQ + 64 + scol);
    #pragma unroll
    for (int j=0;j<4;++j) {
        breg[0][0][j] = *reinterpret_cast<const f32x4*>(brow0 + j*16 + 4*g);
        breg[0][1][j] = *reinterpret_cast<const f32x4*>(brow1 + j*16 + 4*g);
    }
    ATTN_BARRIER();

    float m0s = -__builtin_inff(), l0s = 0.f;
    float m1s = -__builtin_inff(), l1s = 0.f;
    f32x4 accO0[4], accO1[4];
    #pragma unroll
    for (int j=0;j<4;++j) {
        accO0[j] = (f32x4){0.f,0.f,0.f,0.f};
        accO1[j] = (f32x4){0.f,0.f,0.f,0.f};
    }

    for (int t2 = 0; t2 < 32; t2 += 2) {
        ATTN_ITER(0, t2);
        ATTN_ITER(1, t2+1);
    }

    // epilogue: O /= l ; accO{qi}[j][r]: q = w*32+qi*16+4g+r, d = j*16+lr
    {
        float linv = 1.f/l0s;
        float li[4] = { __shfl(linv, 20*g+0), __shfl(linv, 20*g+1),
                        __shfl(linv, 20*g+2), __shfl(linv, 20*g+3) };
        bf16* ob = oh + ((size_t)(b*SEQ + q0 + w*32 + 4*g))*INNER + h*64;
        #pragma unroll
        for (int r=0;r<4;++r)
            #pragma unroll
            for (int j=0;j<4;++j)
                ob[(size_t)r*INNER + j*16 + lr] = (bf16)(accO0[j][r]*li[r]);
    }
    {
        float linv = 1.f/l1s;
        float li[4] = { __shfl(linv, 20*g+0), __shfl(linv, 20*g+1),
                        __shfl(linv, 20*g+2), __shfl(linv, 20*g+3) };
        bf16* ob = oh + ((size_t)(b*SEQ + q0 + 16 + w*32 + 4*g))*INNER + h*64;
        #pragma unroll
        for (int r=0;r<4;++r)
            #pragma unroll
            for (int j=0;j<4;++j)
                ob[(size_t)r*INNER + j*16 + lr] = (bf16)(accO1[j][r]*li[r]);
    }
}

// ---------------- host launcher ----------------
extern "C" void kernel_launch(void* const* d_in, const int* in_sizes, int n_in,
                              void* d_out, int out_size, void* d_ws, size_t ws_size,
                              hipStream_t stream) {
    const float* x    = (const float*)d_in[0];
    const float* bias = (const float*)d_in[1];
    const float* g    = (const float*)d_in[2];
    const float* Wq   = (const float*)d_in[3];
    const float* Wkv  = (const float*)d_in[4];
    const float* Wo   = (const float*)d_in[5];
    float* out = (float*)d_out;

    char* ws = (char*)d_ws;
    bf16*  xn    = (bf16*)(ws);                       //  8,388,608 B (dead after QKV gemm)
    bf16*  vT    = (bf16*)(ws);                       //  overlays xn
    bf16*  wqkv  = (bf16*)(ws + 8388608);             //  6,291,456 B
    bf16*  wo    = (bf16*)(ws + 14680064);            //  2,097,152 B
    bf16*  qkv   = (bf16*)(ws + 16777216);            // 25,165,824 B
    bf16*  oh    = (bf16*)(ws + 41943040);            //  8,388,608 B
    float* psum  = (float*)(ws + 50331648);           //    524,288 B
    float* psq   = (float*)(ws + 50855936);           //    524,288 B
    float* scale = (float*)(ws + 51380224);           //      8,192 B
    float* shift = (float*)(ws + 51388416);           //      8,192 B

    ln_partial <<<dim3(64,2), 256, 0, stream>>>(x, psum, psq);
    ln_finalize<<<dim3(4,2),  256, 0, stream>>>(psum, psq, g, scale, shift);
    ln_apply   <<<dim3(4096), 256, 0, stream>>>(x, scale, shift, xn);

    // Wq prescaled by 0.125*log2e (attention scale folded + exp2-domain softmax)
    castk<<<dim3(1024), 256, 0, stream>>>(Wq,  wqkv,           1048576, 0.125f*LOG2E);
    castk<<<dim3(2048), 256, 0, stream>>>(Wkv, wqkv + 1048576, 2097152, 1.0f);
    castk<<<dim3(1024), 256, 0, stream>>>(Wo,  wo,             1048576, 1.0f);

    // QKV = xn @ [Wq;Wkv]^T : M=4096, N=3072, K=1024
    gemm_bt<bf16><<<dim3(24,32), 256, 0, stream>>>(xn, wqkv, qkv, ROWS, QKVN, DIMD);

    // V -> V^T (per (b,h): [2048 n][64 d] -> [64 d][2048 n]); vT overlays dead xn
    transpose_v<<<dim3(32,16,2), 256, 0, stream>>>(qkv, vT);

    // fused attention (128 q-rows/block) -> out_heads [4096,1024] bf16
    attn_kernel<<<dim3(2,16,16), 256, 0, stream>>>(qkv, vT, bias, oh);

    // final = oh @ Wo^T : M=4096, N=1024, K=1024, fp32 out
    gemm_bt<float><<<dim3(8,32), 256, 0, stream>>>(oh, wo, out, ROWS, INNER, INNER);
}